// Round 9
// baseline (544.064 us; speedup 1.0000x reference)
//
#include <hip/hip_runtime.h>

#define BB 32
#define SS 2048
#define DIN 1024
#define DST 512
#define DH 256   // DST/2
#define NST 64   // MAX_STATES
#define SC 64                   // seq rows per pool chunk
#define CHUNKS (SS / SC)        // 32
#define POOLBLKS (BB * CHUNKS)  // 1024
#define TAG 0x5EEDF00Du

// block map (consumers last so they dispatch after producers)
#define B_HSIMP  POOLBLKS            // 1024
#define B_BCAST0 (POOLBLKS + 1)      // 1025 .. 2048  (1024 blocks)
#define B_H1_0   (B_BCAST0 + 1024)   // 2049 .. 2176  (128 blocks)
#define B_FIN0   (B_H1_0 + 128)      // 2177 .. 2208  (32 blocks)
#define NBLK     (B_FIN0 + 32)       // 2209

__device__ __forceinline__ float dot4(float4 a, float4 b) {
    return a.x * b.x + a.y * b.y + a.z * b.z + a.w * b.w;
}

// Single-dispatch pipeline:
//   producers: pool partials (1024 blocks), hs+imp (1 block), bcast (1024)
//   consumers: h1 (128 blocks), final/mask (32 blocks)
// One-way sync via device-scope flags + __threadfence (G16-sanctioned).
// Deadlock-free: __launch_bounds__(256,2) => >=512 co-resident blocks >> 160
// spinners, and spinners have the highest blockIdx (dispatched last).
__global__ __launch_bounds__(256, 2) void mega(
        const float* __restrict__ x, const float* __restrict__ bank,
        const float* __restrict__ W1, const float* __restrict__ b1,
        const float* __restrict__ W2, const float* __restrict__ b2,
        const float* __restrict__ W3, const float* __restrict__ b3,
        const float* __restrict__ Ws1, const float* __restrict__ bs1,
        const float* __restrict__ Ws2, const float* __restrict__ bs2,
        float* __restrict__ out, float* __restrict__ mask_out,
        float* __restrict__ partial, float* __restrict__ h1,
        float* __restrict__ imp, float* __restrict__ hsbuf,
        unsigned* __restrict__ poolFlag, unsigned* __restrict__ h1Flag,
        unsigned* __restrict__ impFlag) {
    int blk = blockIdx.x, t = threadIdx.x;
    __shared__ float smem[1536];   // role-overlaid scratch (6 KB)

    if (blk < POOLBLKS) {
        // ---------------- pool partial: 64 seq rows summed ------------------
        int b = blk >> 5, c = blk & 31;
        const float4* xp = (const float4*)(x + ((size_t)b * SS + (size_t)c * SC) * DIN);
        float4 acc = make_float4(0.f, 0.f, 0.f, 0.f);
#pragma unroll 8
        for (int s = 0; s < SC; ++s) {
            float4 v = xp[s * (DIN / 4) + t];
            acc.x += v.x; acc.y += v.y; acc.z += v.z; acc.w += v.w;
        }
        ((float4*)(partial + (size_t)blk * DIN))[t] = acc;
        __threadfence();
        __syncthreads();
        if (t == 0) atomicExch(&poolFlag[blk], TAG);
    } else if (blk == B_HSIMP) {
        // ---------------- hs + imp, one block (hidden under pool) -----------
        // thread t = column j; acc[i] = dot(bank_i, Ws1_j) over all 64 states
        float acc[64];
#pragma unroll
        for (int i = 0; i < 64; ++i) acc[i] = 0.f;
        const float4* wrow = (const float4*)(Ws1 + (size_t)t * DST);
        for (int k4 = 0; k4 < DST / 4; ++k4) {
            float4 wv = wrow[k4];
#pragma unroll
            for (int i = 0; i < 64; ++i) {
                float4 bv = ((const float4*)(bank + (size_t)i * DST))[k4]; // uniform
                acc[i] += dot4(bv, wv);
            }
        }
        float hb = bs1[t], w2 = Ws2[t];
#pragma unroll
        for (int i = 0; i < 64; ++i)
            hsbuf[i * 256 + t] = fmaxf(acc[i] + hb, 0.f) * w2;   // coalesced
        __syncthreads();
        if (t < NST) {
            const float4* hv = (const float4*)(hsbuf + t * 256);
            float a = 0.f;
#pragma unroll 8
            for (int k = 0; k < 64; ++k) {
                float4 v = hv[k];
                a += v.x + v.y + v.z + v.w;
            }
            imp[t] = a + bs2[0];
        }
        __threadfence();
        __syncthreads();
        if (t == 0) atomicExch(impFlag, TAG);
    } else if (blk < B_H1_0) {
        // ---------------- bcast state_bank -> allocated_states --------------
        int idx = (blk - B_BCAST0) * 256 + t;   // 262144 float4 = 4 MB
        ((float4*)out)[idx] = ((const float4*)bank)[idx & 8191];
    } else if (blk < B_FIN0) {
        // ---------------- h1 consumer: pool2 + h1 chunk ---------------------
        int q = blk - B_H1_0;
        int b = q >> 2, jc = q & 3;
        if (t == 0) {
            for (int c = 0; c < CHUNKS; ++c)
                while (atomicAdd(&poolFlag[b * CHUNKS + c], 0u) != TAG)
                    __builtin_amdgcn_s_sleep(2);
        }
        __syncthreads();
        __threadfence();   // acquire: drop stale cached lines

        float4* s_pool = (float4*)smem;            // [256] float4
        float* s_a = smem + 1024;                  // [128]
        float* s_b = smem + 1152;                  // [128]

        const float4* src = (const float4*)(partial + (size_t)b * CHUNKS * DIN);
        float4 acc = make_float4(0.f, 0.f, 0.f, 0.f);
#pragma unroll 8
        for (int c = 0; c < CHUNKS; ++c) {
            float4 v = src[c * (DIN / 4) + t];
            acc.x += v.x; acc.y += v.y; acc.z += v.z; acc.w += v.w;
        }
        const float invS = 1.0f / (float)SS;
        acc.x *= invS; acc.y *= invS; acc.z *= invS; acc.w *= invS;
        s_pool[t] = acc;
        __syncthreads();

        int jj = t & 127, half = t >> 7;
        int j = jc * 128 + jj;
        const float4* w = (const float4*)(W1 + (size_t)j * DIN) + half * 128;
        const float4* p = s_pool + half * 128;
        float d0 = 0.f, d1 = 0.f;
#pragma unroll 8
        for (int k = 0; k < 128; k += 2) {
            d0 += dot4(w[k], p[k]);
            d1 += dot4(w[k + 1], p[k + 1]);
        }
        if (half == 0) s_a[jj] = d0 + d1; else s_b[jj] = d0 + d1;
        __syncthreads();
        if (t < 128) {
            int jg = jc * 128 + t;
            h1[(size_t)b * DST + jg] = fmaxf(s_a[t] + s_b[t] + b1[jg], 0.f);
        }
        __threadfence();
        __syncthreads();
        if (t == 0) atomicExch(&h1Flag[q], TAG);
    } else {
        // ---------------- final consumer: h2 -> z -> ns; ranks; mask --------
        int b = blk - B_FIN0;
        if (t == 0) {
            while (atomicAdd(impFlag, 0u) != TAG) __builtin_amdgcn_s_sleep(2);
            for (int q2 = 0; q2 < 4; ++q2)
                while (atomicAdd(&h1Flag[b * 4 + q2], 0u) != TAG)
                    __builtin_amdgcn_s_sleep(2);
        }
        __syncthreads();
        __threadfence();   // acquire

        float4* s_h = (float4*)smem;              // [128] float4 (h1_b)
        float* s_c = smem + 512;                  // [256]
        float* s_imp = smem + 768;                // [64]
        int* s_ns = (int*)(smem + 832);

        if (t < 128) s_h[t] = ((const float4*)(h1 + (size_t)b * DST))[t];
        if (t >= 128 && t < 192) s_imp[t - 128] = imp[t - 128];
        __syncthreads();

        {   // h2_j, j = t: thread reads own W2 row (L2-hot), h1 from LDS
            const float4* w = (const float4*)(W2 + (size_t)t * DST);
            float a0 = 0.f, a1 = 0.f;
#pragma unroll 8
            for (int k = 0; k < 128; k += 2) {
                a0 += dot4(w[k], s_h[k]);
                a1 += dot4(w[k + 1], s_h[k + 1]);
            }
            float h2v = fmaxf(a0 + a1 + b2[t], 0.f);
            s_c[t] = h2v * W3[t];
        }
        __syncthreads();

        if (t < 64) {
            float zp = s_c[t] + s_c[t + 64] + s_c[t + 128] + s_c[t + 192];
            zp += __shfl_xor(zp, 1);
            zp += __shfl_xor(zp, 2);
            zp += __shfl_xor(zp, 4);
            zp += __shfl_xor(zp, 8);
            zp += __shfl_xor(zp, 16);
            zp += __shfl_xor(zp, 32);
            if (t == 0) {
                float z = zp + b3[0];
                float cx = 1.0f / (1.0f + expf(-z));
                int ns = (int)rintf(4.0f + cx * 60.0f);  // round-half-even = jnp.round
                *s_ns = min(max(ns, 4), 64);
            }
        }
        __syncthreads();

        if (t < 64) {
            // rank in descending importance; stable argsort tie-break: lower idx wins
            float mine = s_imp[t];
            int r = 0;
            for (int j2 = 0; j2 < 64; ++j2) {
                float o = s_imp[j2];   // same addr all lanes -> LDS broadcast
                if (o > mine || (o == mine && j2 < t)) ++r;
            }
            mask_out[b * NST + t] = (r < *s_ns) ? 1.0f : 0.0f;
        }
    }
}

extern "C" void kernel_launch(void* const* d_in, const int* in_sizes, int n_in,
                              void* d_out, int out_size, void* d_ws, size_t ws_size,
                              hipStream_t stream) {
    const float* x    = (const float*)d_in[0];
    const float* W1   = (const float*)d_in[1];
    const float* b1   = (const float*)d_in[2];
    const float* W2   = (const float*)d_in[3];
    const float* b2   = (const float*)d_in[4];
    const float* W3   = (const float*)d_in[5];
    const float* b3   = (const float*)d_in[6];
    const float* Ws1  = (const float*)d_in[7];
    const float* bs1  = (const float*)d_in[8];
    const float* Ws2  = (const float*)d_in[9];
    const float* bs2  = (const float*)d_in[10];
    const float* bank = (const float*)d_in[11];
    // d_in[12] = temperature: unused — softmax with positive temp is monotonic,
    // so ranks of raw logits equal ranks of importance.

    float* out = (float*)d_out;
    float* mask_out = out + (size_t)BB * NST * DST;

    float* ws = (float*)d_ws;
    float* partial = ws;                                   // 1024*1024 floats (4 MB)
    float* h1    = partial + (size_t)POOLBLKS * DIN;       // 32*512
    float* imp   = h1 + (size_t)BB * DST;                  // 64
    float* hsbuf = imp + 64;                               // 64*256
    unsigned* poolFlag = (unsigned*)(hsbuf + NST * 256);   // 1024
    unsigned* h1Flag   = poolFlag + POOLBLKS;              // 128
    unsigned* impFlag  = h1Flag + 128;                     // 1

    mega<<<NBLK, 256, 0, stream>>>(x, bank, W1, b1, W2, b2, W3, b3,
                                   Ws1, bs1, Ws2, bs2, out, mask_out,
                                   partial, h1, imp, hsbuf,
                                   poolFlag, h1Flag, impFlag);
}

// Round 10
// 276.662 us; speedup vs baseline: 1.9665x; 1.9665x over previous
//
#include <hip/hip_runtime.h>

#define BB 32
#define SS 2048
#define DIN 1024
#define DST 512
#define DH 256   // DST/2
#define NST 64   // MAX_STATES
#define SC 64                   // seq rows per pool chunk
#define CHUNKS (SS / SC)        // 32
#define POOLBLKS (BB * CHUNKS)  // 1024
#define TAG 0x5EEDF00Du

// block map (consumers last so they dispatch after producers)
#define B_HS0    0                    // 0 .. 63     hs producers
#define B_POOL0  64                   // 64 .. 1087  pool partials
#define B_BCAST0 (B_POOL0 + POOLBLKS) // 1088 .. 2111 bcast
#define B_IMP    (B_BCAST0 + 1024)    // 2112        imp consumer
#define B_H1_0   (B_IMP + 1)          // 2113 .. 2240 h1 consumers (128)
#define B_FIN0   (B_H1_0 + 128)       // 2241 .. 2272 final consumers (32)
#define NBLK     (B_FIN0 + 32)        // 2273

__device__ __forceinline__ float dot4(float4 a, float4 b) {
    return a.x * b.x + a.y * b.y + a.z * b.z + a.w * b.w;
}

// Single-dispatch pipeline; all heavy branches are the PROVEN R8 kernels.
// One-way sync via device-scope flags + __threadfence (G16-sanctioned).
// Deadlock-free: __launch_bounds__(256,2) => >=512 co-resident blocks >> 161
// spinners, and spinners have the highest blockIdx (dispatched last).
// No per-thread arrays anywhere (R9's acc[64] spilled to scratch: 640us).
__global__ __launch_bounds__(256, 2) void mega(
        const float* __restrict__ x, const float* __restrict__ bank,
        const float* __restrict__ W1, const float* __restrict__ b1,
        const float* __restrict__ W2, const float* __restrict__ b2,
        const float* __restrict__ W3, const float* __restrict__ b3,
        const float* __restrict__ Ws1, const float* __restrict__ bs1,
        const float* __restrict__ Ws2, const float* __restrict__ bs2,
        float* __restrict__ out, float* __restrict__ mask_out,
        float* __restrict__ partial, float* __restrict__ h1,
        float* __restrict__ imp, float* __restrict__ hsbuf,
        unsigned* __restrict__ poolFlag, unsigned* __restrict__ hsFlag,
        unsigned* __restrict__ h1Flag, unsigned* __restrict__ impFlag) {
    int blk = blockIdx.x, t = threadIdx.x;
    __shared__ float smem[1536];   // role-overlaid scratch (6 KB)

    if (blk < B_POOL0) {
        // -------- hs producer: hs[i][j] for j in [4g,4g+4), all 64 i --------
        int g = blk;
        int i = t & 63;
        int j = g * 4 + (t >> 6);
        const float4* w = (const float4*)(Ws1 + (size_t)j * DST);  // bcast among lanes
        const float4* s = (const float4*)(bank + (size_t)i * DST);
        float a0 = 0.f, a1 = 0.f;
#pragma unroll 8
        for (int k = 0; k < DST / 4; k += 2) {
            a0 += dot4(w[k], s[k]);
            a1 += dot4(w[k + 1], s[k + 1]);
        }
        hsbuf[(size_t)i * DH + j] = fmaxf(a0 + a1 + bs1[j], 0.f);
        __threadfence();
        __syncthreads();
        if (t == 0) atomicExch(&hsFlag[g], TAG);
    } else if (blk < B_BCAST0) {
        // -------- pool partial: 64 seq rows summed --------------------------
        int task = blk - B_POOL0;
        int b = task >> 5, c = task & 31;
        const float4* xp = (const float4*)(x + ((size_t)b * SS + (size_t)c * SC) * DIN);
        float4 acc = make_float4(0.f, 0.f, 0.f, 0.f);
#pragma unroll 8
        for (int s = 0; s < SC; ++s) {
            float4 v = xp[s * (DIN / 4) + t];
            acc.x += v.x; acc.y += v.y; acc.z += v.z; acc.w += v.w;
        }
        ((float4*)(partial + (size_t)task * DIN))[t] = acc;
        __threadfence();
        __syncthreads();
        if (t == 0) atomicExch(&poolFlag[task], TAG);
    } else if (blk < B_IMP) {
        // -------- bcast state_bank -> allocated_states ----------------------
        int idx = (blk - B_BCAST0) * 256 + t;   // 262144 float4 = 4 MB
        ((float4*)out)[idx] = ((const float4*)bank)[idx & 8191];
    } else if (blk == B_IMP) {
        // -------- imp consumer: imp[i] = dot(hs_i, Ws2) + bs2 ---------------
        if (t < 64)
            while (atomicAdd(&hsFlag[t], 0u) != TAG) __builtin_amdgcn_s_sleep(2);
        __syncthreads();
        __threadfence();   // acquire
        if (t < NST) {
            const float4* hv = (const float4*)(hsbuf + (size_t)t * DH);
            const float4* w  = (const float4*)(Ws2);
            float a = 0.f;
#pragma unroll 8
            for (int k = 0; k < DH / 4; ++k) a += dot4(hv[k], w[k]);
            imp[t] = a + bs2[0];
        }
        __threadfence();
        __syncthreads();
        if (t == 0) atomicExch(impFlag, TAG);
    } else if (blk < B_FIN0) {
        // -------- h1 consumer: in-LDS pool2 + h1 chunk ----------------------
        int q = blk - B_H1_0;
        int b = q >> 2, jc = q & 3;
        if (t < CHUNKS)
            while (atomicAdd(&poolFlag[b * CHUNKS + t], 0u) != TAG)
                __builtin_amdgcn_s_sleep(2);
        __syncthreads();
        __threadfence();   // acquire

        float4* s_pool = (float4*)smem;            // [256] float4
        float* s_a = smem + 1024;                  // [128]
        float* s_b = smem + 1152;                  // [128]

        const float4* src = (const float4*)(partial + (size_t)b * CHUNKS * DIN);
        float4 acc = make_float4(0.f, 0.f, 0.f, 0.f);
#pragma unroll 8
        for (int c = 0; c < CHUNKS; ++c) {
            float4 v = src[c * (DIN / 4) + t];
            acc.x += v.x; acc.y += v.y; acc.z += v.z; acc.w += v.w;
        }
        const float invS = 1.0f / (float)SS;
        acc.x *= invS; acc.y *= invS; acc.z *= invS; acc.w *= invS;
        s_pool[t] = acc;
        __syncthreads();

        int jj = t & 127, half = t >> 7;
        int j = jc * 128 + jj;
        const float4* w = (const float4*)(W1 + (size_t)j * DIN) + half * 128;
        const float4* p = s_pool + half * 128;
        float d0 = 0.f, d1 = 0.f;
#pragma unroll 8
        for (int k = 0; k < 128; k += 2) {
            d0 += dot4(w[k], p[k]);
            d1 += dot4(w[k + 1], p[k + 1]);
        }
        if (half == 0) s_a[jj] = d0 + d1; else s_b[jj] = d0 + d1;
        __syncthreads();
        if (t < 128) {
            int jg = jc * 128 + t;
            h1[(size_t)b * DST + jg] = fmaxf(s_a[t] + s_b[t] + b1[jg], 0.f);
        }
        __threadfence();
        __syncthreads();
        if (t == 0) atomicExch(&h1Flag[q], TAG);
    } else {
        // -------- final consumer: h2 -> z -> ns; ranks; mask ----------------
        int b = blk - B_FIN0;
        if (t < 4)
            while (atomicAdd(&h1Flag[b * 4 + t], 0u) != TAG)
                __builtin_amdgcn_s_sleep(2);
        if (t == 4)
            while (atomicAdd(impFlag, 0u) != TAG) __builtin_amdgcn_s_sleep(2);
        __syncthreads();
        __threadfence();   // acquire

        float4* s_h = (float4*)smem;              // [128] float4 (h1_b)
        float* s_c = smem + 512;                  // [256]
        float* s_imp = smem + 768;                // [64]
        int* s_ns = (int*)(smem + 832);

        if (t < 128) s_h[t] = ((const float4*)(h1 + (size_t)b * DST))[t];
        if (t >= 128 && t < 192) s_imp[t - 128] = imp[t - 128];
        __syncthreads();

        {   // h2_j, j = t: thread reads own W2 row (L2-hot), h1 from LDS
            const float4* w = (const float4*)(W2 + (size_t)t * DST);
            float a0 = 0.f, a1 = 0.f;
#pragma unroll 8
            for (int k = 0; k < 128; k += 2) {
                a0 += dot4(w[k], s_h[k]);
                a1 += dot4(w[k + 1], s_h[k + 1]);
            }
            float h2v = fmaxf(a0 + a1 + b2[t], 0.f);
            s_c[t] = h2v * W3[t];
        }
        __syncthreads();

        if (t < 64) {
            float zp = s_c[t] + s_c[t + 64] + s_c[t + 128] + s_c[t + 192];
            zp += __shfl_xor(zp, 1);
            zp += __shfl_xor(zp, 2);
            zp += __shfl_xor(zp, 4);
            zp += __shfl_xor(zp, 8);
            zp += __shfl_xor(zp, 16);
            zp += __shfl_xor(zp, 32);
            if (t == 0) {
                float z = zp + b3[0];
                float cx = 1.0f / (1.0f + expf(-z));
                int ns = (int)rintf(4.0f + cx * 60.0f);  // round-half-even = jnp.round
                *s_ns = min(max(ns, 4), 64);
            }
        }
        __syncthreads();

        if (t < 64) {
            // rank in descending importance; stable argsort tie-break: lower idx wins
            float mine = s_imp[t];
            int r = 0;
            for (int j2 = 0; j2 < 64; ++j2) {
                float o = s_imp[j2];   // same addr all lanes -> LDS broadcast
                if (o > mine || (o == mine && j2 < t)) ++r;
            }
            mask_out[b * NST + t] = (r < *s_ns) ? 1.0f : 0.0f;
        }
    }
}

extern "C" void kernel_launch(void* const* d_in, const int* in_sizes, int n_in,
                              void* d_out, int out_size, void* d_ws, size_t ws_size,
                              hipStream_t stream) {
    const float* x    = (const float*)d_in[0];
    const float* W1   = (const float*)d_in[1];
    const float* b1   = (const float*)d_in[2];
    const float* W2   = (const float*)d_in[3];
    const float* b2   = (const float*)d_in[4];
    const float* W3   = (const float*)d_in[5];
    const float* b3   = (const float*)d_in[6];
    const float* Ws1  = (const float*)d_in[7];
    const float* bs1  = (const float*)d_in[8];
    const float* Ws2  = (const float*)d_in[9];
    const float* bs2  = (const float*)d_in[10];
    const float* bank = (const float*)d_in[11];
    // d_in[12] = temperature: unused — softmax with positive temp is monotonic,
    // so ranks of raw logits equal ranks of importance.

    float* out = (float*)d_out;
    float* mask_out = out + (size_t)BB * NST * DST;

    float* ws = (float*)d_ws;
    float* partial = ws;                                   // 1024*1024 floats (4 MB)
    float* h1    = partial + (size_t)POOLBLKS * DIN;       // 32*512
    float* imp   = h1 + (size_t)BB * DST;                  // 64
    float* hsbuf = imp + 64;                               // 64*256
    unsigned* poolFlag = (unsigned*)(hsbuf + NST * DH);    // 1024
    unsigned* hsFlag   = poolFlag + POOLBLKS;              // 64
    unsigned* h1Flag   = hsFlag + 64;                      // 128
    unsigned* impFlag  = h1Flag + 128;                     // 1

    mega<<<NBLK, 256, 0, stream>>>(x, bank, W1, b1, W2, b2, W3, b3,
                                   Ws1, bs1, Ws2, bs2, out, mask_out,
                                   partial, h1, imp, hsbuf,
                                   poolFlag, hsFlag, h1Flag, impFlag);
}

// Round 11
// 152.279 us; speedup vs baseline: 3.5728x; 1.8168x over previous
//
#include <hip/hip_runtime.h>

#define BB 32
#define SS 2048
#define DIN 1024
#define DST 512
#define DH 256   // DST/2
#define NST 64   // MAX_STATES
#define SC 64                   // seq rows per pool chunk
#define CHUNKS (SS / SC)        // 32
#define POOLBLKS (BB * CHUNKS)  // 1024

__device__ __forceinline__ float dot4(float4 a, float4 b) {
    return a.x * b.x + a.y * b.y + a.z * b.z + a.w * b.w;
}

// ============ D1: pool partials (1024 blocks) + hs rows (64 blocks) =========
__global__ void kA(const float* __restrict__ x, const float* __restrict__ bank,
                   const float* __restrict__ Ws1, const float* __restrict__ bs1,
                   float* __restrict__ partial, float* __restrict__ hsbuf) {
    int blk = blockIdx.x, t = threadIdx.x;
    if (blk < POOLBLKS) {
        int b = blk >> 5;        // batch
        int c = blk & 31;        // chunk of 64 seq rows
        const float4* xp = (const float4*)(x + ((size_t)b * SS + (size_t)c * SC) * DIN);
        float4 acc = make_float4(0.f, 0.f, 0.f, 0.f);
#pragma unroll 8
        for (int s = 0; s < SC; ++s) {
            float4 v = xp[s * (DIN / 4) + t];
            acc.x += v.x; acc.y += v.y; acc.z += v.z; acc.w += v.w;
        }
        ((float4*)(partial + (size_t)blk * DIN))[t] = acc;
    } else {
        // hs[i][j] = relu(dot(bank_i, Ws1_j) + bs1_j); j = g*4 + (t>>6), i = t&63
        int g = blk - POOLBLKS;
        int i = t & 63;
        int j = g * 4 + (t >> 6);
        const float4* w = (const float4*)(Ws1 + (size_t)j * DST);  // bcast among lanes
        const float4* s = (const float4*)(bank + (size_t)i * DST);
        float a0 = 0.f, a1 = 0.f;
#pragma unroll 8
        for (int k = 0; k < DST / 4; k += 2) {
            a0 += dot4(w[k], s[k]);
            a1 += dot4(w[k + 1], s[k + 1]);
        }
        hsbuf[(size_t)i * DH + j] = fmaxf(a0 + a1 + bs1[j], 0.f);
    }
}

// ============ D2: 32 fat per-batch blocks + 1024 bcast blocks ===============
// Fat block b: pool2 -> h1 (full W1, 2-pass, L1-friendly row dots) -> h2 ->
// imp -> z/sigmoid/ns -> ranks -> mask row. No cross-block deps.
__global__ __launch_bounds__(256) void kB(
        const float* __restrict__ partial,
        const float* __restrict__ W1, const float* __restrict__ b1,
        const float* __restrict__ W2, const float* __restrict__ b2,
        const float* __restrict__ W3, const float* __restrict__ b3,
        const float* __restrict__ hsbuf,
        const float* __restrict__ Ws2, const float* __restrict__ bs2,
        const float* __restrict__ bank,
        float* __restrict__ out, float* __restrict__ mask_out) {
    int blk = blockIdx.x, t = threadIdx.x;
    if (blk >= BB) {
        // bcast state_bank -> allocated_states (uses the 224 idle CUs)
        int idx = (blk - BB) * 256 + t;   // 1024*256 = 262144 float4 = 4 MB
        ((float4*)out)[idx] = ((const float4*)bank)[idx & 8191];
        return;
    }
    int b = blk;
    __shared__ float4 s_pool[256];   // pooled_b (1024 floats)
    __shared__ float s_h1[DST];
    __shared__ float s_c[DH];        // h2_j * W3_j
    __shared__ float s_imp[NST];
    __shared__ int s_ns;

    // ---- stage A: pool2 (reads 128 KB, coalesced, L2/L3) -------------------
    const float4* src = (const float4*)(partial + (size_t)b * CHUNKS * DIN);
    float4 acc = make_float4(0.f, 0.f, 0.f, 0.f);
#pragma unroll 8
    for (int c = 0; c < CHUNKS; ++c) {
        float4 v = src[c * (DIN / 4) + t];
        acc.x += v.x; acc.y += v.y; acc.z += v.z; acc.w += v.w;
    }
    const float invS = 1.0f / (float)SS;
    acc.x *= invS; acc.y *= invS; acc.z *= invS; acc.w *= invS;
    s_pool[t] = acc;

    // ---- imp (independent of pool; hsbuf from D1, L2-hot 64 KB) ------------
    if (t < NST) {
        const float4* hv = (const float4*)(hsbuf + (size_t)t * DH);
        const float4* w  = (const float4*)(Ws2);
        float a = 0.f;
#pragma unroll 8
        for (int k = 0; k < DH / 4; ++k) a += dot4(hv[k], w[k]);
        s_imp[t] = a + bs2[0];
    }
    __syncthreads();

    // ---- stage B: h1, 2 passes of 256 rows (16 KB line footprint <= L1) ----
#pragma unroll
    for (int p = 0; p < 2; ++p) {
        int j = p * 256 + t;
        const float4* w = (const float4*)(W1 + (size_t)j * DIN);
        float d0 = 0.f, d1 = 0.f;
#pragma unroll 16
        for (int k = 0; k < DIN / 4; k += 2) {
            d0 += dot4(w[k], s_pool[k]);
            d1 += dot4(w[k + 1], s_pool[k + 1]);
        }
        s_h1[j] = fmaxf(d0 + d1 + b1[j], 0.f);
    }
    __syncthreads();

    // ---- stage C: h2_j, j = t (thread reads own W2 row) --------------------
    {
        const float4* w = (const float4*)(W2 + (size_t)t * DST);
        const float4* hv = (const float4*)s_h1;
        float d0 = 0.f, d1 = 0.f;
#pragma unroll 16
        for (int k = 0; k < DST / 4; k += 2) {
            d0 += dot4(w[k], hv[k]);
            d1 += dot4(w[k + 1], hv[k + 1]);
        }
        float h2v = fmaxf(d0 + d1 + b2[t], 0.f);
        s_c[t] = h2v * W3[t];
    }
    __syncthreads();

    // ---- stage D: z -> sigmoid -> num_states -------------------------------
    if (t < 64) {
        float zp = s_c[t] + s_c[t + 64] + s_c[t + 128] + s_c[t + 192];
        zp += __shfl_xor(zp, 1);
        zp += __shfl_xor(zp, 2);
        zp += __shfl_xor(zp, 4);
        zp += __shfl_xor(zp, 8);
        zp += __shfl_xor(zp, 16);
        zp += __shfl_xor(zp, 32);
        if (t == 0) {
            float z = zp + b3[0];
            float cx = 1.0f / (1.0f + expf(-z));
            int ns = (int)rintf(4.0f + cx * 60.0f);   // round-half-even = jnp.round
            s_ns = min(max(ns, 4), 64);
        }
    }
    __syncthreads();

    // ---- stage E: ranks + mask row -----------------------------------------
    if (t < 64) {
        // rank in descending importance; stable argsort tie-break: lower idx wins
        float mine = s_imp[t];
        int r = 0;
        for (int j2 = 0; j2 < 64; ++j2) {
            float o = s_imp[j2];   // same addr all lanes -> LDS broadcast
            if (o > mine || (o == mine && j2 < t)) ++r;
        }
        mask_out[b * NST + t] = (r < s_ns) ? 1.0f : 0.0f;
    }
}

extern "C" void kernel_launch(void* const* d_in, const int* in_sizes, int n_in,
                              void* d_out, int out_size, void* d_ws, size_t ws_size,
                              hipStream_t stream) {
    const float* x    = (const float*)d_in[0];
    const float* W1   = (const float*)d_in[1];
    const float* b1   = (const float*)d_in[2];
    const float* W2   = (const float*)d_in[3];
    const float* b2   = (const float*)d_in[4];
    const float* W3   = (const float*)d_in[5];
    const float* b3   = (const float*)d_in[6];
    const float* Ws1  = (const float*)d_in[7];
    const float* bs1  = (const float*)d_in[8];
    const float* Ws2  = (const float*)d_in[9];
    const float* bs2  = (const float*)d_in[10];
    const float* bank = (const float*)d_in[11];
    // d_in[12] = temperature: unused — softmax with positive temp is monotonic,
    // so ranks of raw logits equal ranks of importance.

    float* out = (float*)d_out;
    float* mask_out = out + (size_t)BB * NST * DST;

    float* ws = (float*)d_ws;
    float* partial = ws;                                   // 1024*1024 floats (4 MB)
    float* hsbuf = partial + (size_t)POOLBLKS * DIN;       // 64*256

    kA<<<POOLBLKS + 64, 256, 0, stream>>>(x, bank, Ws1, bs1, partial, hsbuf);
    kB<<<BB + 1024, 256, 0, stream>>>(partial, W1, b1, W2, b2, W3, b3,
                                      hsbuf, Ws2, bs2, bank, out, mask_out);
}

// Round 12
// 107.577 us; speedup vs baseline: 5.0574x; 1.4155x over previous
//
#include <hip/hip_runtime.h>

#define BB 32
#define SS 2048
#define DIN 1024
#define DST 512
#define DH 256   // DST/2
#define NST 64   // MAX_STATES
#define SC 64                   // seq rows per pool chunk
#define CHUNKS (SS / SC)        // 32
#define POOLBLKS (BB * CHUNKS)  // 1024

__device__ __forceinline__ float dot4(float4 a, float4 b) {
    return a.x * b.x + a.y * b.y + a.z * b.z + a.w * b.w;
}

// ============ kA: pool partials [0,1024) + hs rows [1024,1088) + bcast ======
// Proven R8 structure: no shuffle chains, no per-thread arrays, no sync.
__global__ void kA(const float* __restrict__ x, const float* __restrict__ bank,
                   const float* __restrict__ Ws1, const float* __restrict__ bs1,
                   float* __restrict__ partial, float* __restrict__ hs,
                   float* __restrict__ out) {
    int blk = blockIdx.x, t = threadIdx.x;
    if (blk < POOLBLKS) {
        int b = blk >> 5;        // batch
        int c = blk & 31;        // chunk of 64 seq rows
        const float4* xp = (const float4*)(x + ((size_t)b * SS + (size_t)c * SC) * DIN);
        float4 acc = make_float4(0.f, 0.f, 0.f, 0.f);
#pragma unroll 8
        for (int s = 0; s < SC; ++s) {
            float4 v = xp[s * (DIN / 4) + t];
            acc.x += v.x; acc.y += v.y; acc.z += v.z; acc.w += v.w;
        }
        ((float4*)(partial + (size_t)blk * DIN))[t] = acc;
    } else if (blk < POOLBLKS + 64) {
        // hs[i][j] = relu(dot(bank_i, Ws1_j) + bs1_j); j = g*4 + (t>>6), i = t&63
        int g = blk - POOLBLKS;
        int i = t & 63;
        int j = g * 4 + (t >> 6);
        const float4* w = (const float4*)(Ws1 + (size_t)j * DST);  // broadcast among 64 lanes
        const float4* s = (const float4*)(bank + (size_t)i * DST);
        float a0 = 0.f, a1 = 0.f;
#pragma unroll 8
        for (int k = 0; k < DST / 4; k += 2) {
            a0 += dot4(w[k], s[k]);
            a1 += dot4(w[k + 1], s[k + 1]);
        }
        hs[(size_t)i * DH + j] = fmaxf(a0 + a1 + bs1[j], 0.f);
    } else {
        int idx = (blk - (POOLBLKS + 64)) * 256 + t;  // 1024*256 = 262144 float4
        ((float4*)out)[idx] = ((const float4*)bank)[idx & 8191];
    }
}

// ============ kB: [0,128) in-LDS pool2 + h1 chunk; block 128 = imp ==========
// h1: 2 threads per output j (k-split halves), single LDS combine, no shuffles.
// imp: thread-per-state full row dot, no shuffles.
__global__ void kB(const float* __restrict__ partial,
                   const float* __restrict__ W1, const float* __restrict__ b1,
                   const float* __restrict__ hs,
                   const float* __restrict__ Ws2, const float* __restrict__ bs2,
                   float* __restrict__ h1, float* __restrict__ imp) {
    int blk = blockIdx.x, t = threadIdx.x;
    if (blk < 128) {
        int b = blk >> 2, jc = blk & 3;
        __shared__ float4 s_pool[256];   // pooled_b (1024 floats)
        __shared__ float s_a[128], s_b[128];

        // stage A: reduce 32 partial chunks -> pooled_b (mean), into LDS
        const float4* src = (const float4*)(partial + (size_t)b * CHUNKS * DIN);
        float4 acc = make_float4(0.f, 0.f, 0.f, 0.f);
#pragma unroll 8
        for (int c = 0; c < CHUNKS; ++c) {
            float4 v = src[c * (DIN / 4) + t];
            acc.x += v.x; acc.y += v.y; acc.z += v.z; acc.w += v.w;
        }
        const float invS = 1.0f / (float)SS;
        acc.x *= invS; acc.y *= invS; acc.z *= invS; acc.w *= invS;
        s_pool[t] = acc;
        __syncthreads();

        // stage B: h1 rows jc*128..+127; thread (jj, half) dots 512 elems
        int jj = t & 127, half = t >> 7;
        int j = jc * 128 + jj;
        const float4* w = (const float4*)(W1 + (size_t)j * DIN) + half * 128;
        const float4* p = s_pool + half * 128;
        float d0 = 0.f, d1 = 0.f;
#pragma unroll 8
        for (int k = 0; k < 128; k += 2) {
            d0 += dot4(w[k], p[k]);
            d1 += dot4(w[k + 1], p[k + 1]);
        }
        if (half == 0) s_a[jj] = d0 + d1; else s_b[jj] = d0 + d1;
        __syncthreads();
        if (t < 128) {
            int jg = jc * 128 + t;
            h1[(size_t)b * DST + jg] = fmaxf(s_a[t] + s_b[t] + b1[jg], 0.f);
        }
    } else if (t < NST) {
        // imp[i] = dot(hs_i, Ws2) + bs2; thread-per-state, Ws2 broadcast
        const float4* hv = (const float4*)(hs + (size_t)t * DH);
        const float4* w  = (const float4*)(Ws2);
        float a = 0.f;
#pragma unroll 8
        for (int k = 0; k < DH / 4; ++k) a += dot4(hv[k], w[k]);
        imp[t] = a + bs2[0];
    }
}

// ============ kC: per-batch: h2 (thread-per-j) -> z -> ns; ranks; mask ======
// One LDS fold + ONE 6-shfl reduce per block total.
__global__ void kC(const float* __restrict__ h1,
                   const float* __restrict__ W2, const float* __restrict__ b2,
                   const float* __restrict__ W3, const float* __restrict__ b3,
                   const float* __restrict__ imp, float* __restrict__ mask_out) {
    int b = blockIdx.x, t = threadIdx.x;
    __shared__ float4 s_h[128];     // h1_b (512 floats)
    __shared__ float s_c[DH];       // h2_j * W3_j
    __shared__ float s_imp[NST];
    __shared__ int s_ns;

    if (t < 128) s_h[t] = ((const float4*)(h1 + (size_t)b * DST))[t];
    if (t >= 128 && t < 192) s_imp[t - 128] = imp[t - 128];
    __syncthreads();

    // h2_j: j = t, each thread reads its own W2 row (L2-hot), h1 from LDS
    {
        const float4* w = (const float4*)(W2 + (size_t)t * DST);
        float a0 = 0.f, a1 = 0.f;
#pragma unroll 8
        for (int k = 0; k < 128; k += 2) {
            a0 += dot4(w[k], s_h[k]);
            a1 += dot4(w[k + 1], s_h[k + 1]);
        }
        float h2v = fmaxf(a0 + a1 + b2[t], 0.f);
        s_c[t] = h2v * W3[t];
    }
    __syncthreads();

    if (t < 64) {
        float zp = s_c[t] + s_c[t + 64] + s_c[t + 128] + s_c[t + 192];
        zp += __shfl_xor(zp, 1);
        zp += __shfl_xor(zp, 2);
        zp += __shfl_xor(zp, 4);
        zp += __shfl_xor(zp, 8);
        zp += __shfl_xor(zp, 16);
        zp += __shfl_xor(zp, 32);
        if (t == 0) {
            float z = zp + b3[0];
            float cx = 1.0f / (1.0f + expf(-z));
            int ns = (int)rintf(4.0f + cx * 60.0f);   // round-half-even = jnp.round
            s_ns = min(max(ns, 4), 64);
        }
    }
    __syncthreads();

    if (t < 64) {
        // rank in descending importance; stable argsort tie-break: lower idx wins
        float mine = s_imp[t];
        int r = 0;
        for (int j2 = 0; j2 < 64; ++j2) {
            float o = s_imp[j2];   // same addr all lanes -> LDS broadcast
            if (o > mine || (o == mine && j2 < t)) ++r;
        }
        mask_out[b * NST + t] = (r < s_ns) ? 1.0f : 0.0f;
    }
}

extern "C" void kernel_launch(void* const* d_in, const int* in_sizes, int n_in,
                              void* d_out, int out_size, void* d_ws, size_t ws_size,
                              hipStream_t stream) {
    const float* x    = (const float*)d_in[0];
    const float* W1   = (const float*)d_in[1];
    const float* b1   = (const float*)d_in[2];
    const float* W2   = (const float*)d_in[3];
    const float* b2   = (const float*)d_in[4];
    const float* W3   = (const float*)d_in[5];
    const float* b3   = (const float*)d_in[6];
    const float* Ws1  = (const float*)d_in[7];
    const float* bs1  = (const float*)d_in[8];
    const float* Ws2  = (const float*)d_in[9];
    const float* bs2  = (const float*)d_in[10];
    const float* bank = (const float*)d_in[11];
    // d_in[12] = temperature: unused — softmax with positive temp is monotonic,
    // so ranks of raw logits equal ranks of importance.

    float* out = (float*)d_out;
    float* mask_out = out + (size_t)BB * NST * DST;

    float* ws = (float*)d_ws;
    float* partial = ws;                                   // 1024*1024 floats (4 MB)
    float* hs  = partial + (size_t)POOLBLKS * DIN;         // 64*256
    float* h1  = hs + (size_t)NST * DH;                    // 32*512
    float* imp = h1 + (size_t)BB * DST;                    // 64

    kA<<<POOLBLKS + 64 + 1024, 256, 0, stream>>>(x, bank, Ws1, bs1, partial, hs, out);
    kB<<<129, 256, 0, stream>>>(partial, W1, b1, hs, Ws2, bs2, h1, imp);
    kC<<<32, 256, 0, stream>>>(h1, W2, b2, W3, b3, imp, mask_out);
}